// Round 17
// baseline (207.773 us; speedup 1.0000x reference)
//
#include <hip/hip_runtime.h>
#include <math.h>

#define BB 16
#define TT 4096
#define EE 1024
#define HALF 2048
#define WIN 15
#define EPSF 1e-6f
#define PI_F   3.14159265358979323846f
#define PIO2_F 1.57079632679489662f

// Minimal-issue branchless asin of clamp(t): ~18 VALU slots, raw HW sqrt.
__device__ __forceinline__ float asin_clamped(float t, float LO, float HI) {
    float c  = __builtin_amdgcn_fmed3f(t, LO, HI);   // clamp (1 op, no NaN here)
    float a  = fabsf(c);
    float z1 = c * c;
    float z2 = fmaf(a, -0.5f, 0.5f);                 // (1-a)/2
    bool big = a > 0.5f;
    float z  = big ? z2 : z1;
    float sq;
    asm("v_sqrt_f32 %0, %1" : "=v"(sq) : "v"(z2));   // raw, no IEEE fixup chain
    float s  = big ? sq : a;                         // s in [0, 0.5]
    float p = fmaf(z, 4.2163199048e-2f, 2.4181311049e-2f);
    p = fmaf(z, p, 4.5470025998e-2f);
    p = fmaf(z, p, 7.4953002686e-2f);
    p = fmaf(z, p, 1.6666752422e-1f);
    float r  = fmaf(s * z, p, s);                    // asin(s)
    float rb = fmaf(-2.0f, r, PIO2_F);               // pi/2 - 2*asin(s)
    r = big ? rb : r;
    return copysignf(r, c);
}

// ---------------------------------------------------------------------------
// Phase + fused tdiff (R15 frontier, verbatim): wave per row, b-major out.
// ---------------------------------------------------------------------------
__global__ void phase_tdiff_kernel(const float* __restrict__ x,
                                   const float* __restrict__ taper,
                                   float* __restrict__ phases_b,
                                   float* __restrict__ tdiff_b) {
    const int wave = threadIdx.x >> 6;
    const int lane = threadIdx.x & 63;
    const int row  = blockIdx.x * 4 + wave;      // [0, B*T)
    const int b = row >> 12;
    const int t = row & (TT - 1);
    const float tap = taper[t];
    const float* xr = x + (size_t)row * EE;

    float xd = 0.0f, tapd = 0.0f;
    const int td = t - lane;
    const bool do_d = (lane >= 1) && (lane <= WIN) && (lane <= t);
    if (do_d) {
        xd   = x[((size_t)b * TT + td) * EE];    // element 0 of row t-lane
        tapd = taper[td];
    }

    const float c0 = xr[0] * tap;
    const float r = fabsf(c0) + EPSF;
    const float scale = tap / r;
    const float start = (c0 >= 0.0f) ? 0.0f : PI_F;
    const float LO = -1.0f + EPSF, HI = 1.0f - EPSF;

    const float4* xr4 = (const float4*)xr;
    float sum = 0.0f;
    #pragma unroll
    for (int j = 0; j < 4; ++j) {
        float4 v = xr4[j * 64 + lane];
        float a0 = asin_clamped(v.x * scale, LO, HI);
        if ((j | lane) == 0) a0 = 0.0f;          // element 0 excluded
        sum += a0;
        sum += asin_clamped(v.y * scale, LO, HI);
        sum += asin_clamped(v.z * scale, LO, HI);
        sum += asin_clamped(v.w * scale, LO, HI);
    }
    #pragma unroll
    for (int off = 32; off > 0; off >>= 1)
        sum += __shfl_xor(sum, off, 64);

    float contrib = do_d ? ((float)lane * xd * tapd) : 0.0f;
    #pragma unroll
    for (int off = 8; off > 0; off >>= 1)
        contrib += __shfl_xor(contrib, off, 64);

    if (lane == 0) {
        phases_b[b * TT + t] = start + sum;
        const int s = (t < WIN) ? t : WIN;
        const float norm = 0.5f * (float)s * (float)(s + 1);
        tdiff_b[b * TT + t] = (norm > 0.0f) ? (contrib / norm) : 0.0f;
    }
}

// ---------------------------------------------------------------------------
// GEMM (M=16), WHOLE-CHUNK LDS: stage a [16][2048] A-chunk (128.2 KB) into
// LDS in ONE shot, weights for the whole chunk preloaded into registers,
// then barrier-free compute. G1 = 2 chunks (3 barriers total), G2 = 1 chunk
// (1 barrier). 256 blocks x 512 threads (1 block/CU), 16 cols/block
// (2 per wave). Kills the per-tile barrier structure that capped R9-R16.
// MODE 0: silu -> H_b[b*HALF + o].  MODE 1: tanh -> out[b*4096 + o*2 + g].
// ---------------------------------------------------------------------------
__device__ __forceinline__ void gld_lds16(const float* g, float* l) {
    __builtin_amdgcn_global_load_lds(
        (const __attribute__((address_space(1))) unsigned int*)g,
        (__attribute__((address_space(3))) unsigned int*)l,
        16, 0, 0);
}

template <int K, int MODE>
__global__ void __launch_bounds__(512)
gemm_kernel(const float* __restrict__ A0, const float* __restrict__ W0,
            const float* __restrict__ bias0, float* __restrict__ out0,
            const float* __restrict__ A1, const float* __restrict__ W1,
            const float* __restrict__ bias1, float* __restrict__ out1) {
    constexpr int CK = 2048;                      // K-chunk held fully in LDS
    constexpr int NC = K / CK;                    // 2 (G1) / 1 (G2)
    constexpr int LR = CK + 4;                    // row stride, 16B-aligned
    __shared__ float als[16 * LR];                // 128.25 KiB -> 1 block/CU

    const int nb = HALF / 16;                     // 128 blocks per problem
    const int g = blockIdx.x / nb;
    const int obase = (blockIdx.x % nb) * 16;

    const float* A    = g ? A1 : A0;
    const float* W    = g ? W1 : W0;
    const float* bias = g ? bias1 : bias0;
    float* out        = g ? out1 : out0;

    const int wv   = threadIdx.x >> 6;            // 0..7
    const int lane = threadIdx.x & 63;
    const int col0 = obase + wv * 2;
    const int col1 = col0 + 1;
    const float* w0p = W + (size_t)col0 * K;
    const float* w1p = W + (size_t)col1 * K;

    float acc0[16], acc1[16];
    #pragma unroll
    for (int i = 0; i < 16; ++i) { acc0[i] = 0.0f; acc1[i] = 0.0f; }

    #pragma unroll 1
    for (int c = 0; c < NC; ++c) {
        if (c > 0) __syncthreads();               // als free (prev compute done)

        // stage A chunk: wave wv stages rows 2wv, 2wv+1 (8 x 1KiB each)
        #pragma unroll
        for (int i = 0; i < 2; ++i) {
            const int br = wv * 2 + i;
            const float* src = A + (size_t)br * K + c * CK + lane * 4;
            float* dst = &als[br * LR];           // uniform base; HW adds lane*16B
            #pragma unroll
            for (int s = 0; s < 8; ++s)
                gld_lds16(src + s * 256, dst + s * 256);
        }

        // whole-chunk weights -> registers (latency shared with the stage)
        float4 w0r[8], w1r[8];
        #pragma unroll
        for (int s = 0; s < 8; ++s) {
            w0r[s] = *(const float4*)(w0p + c * CK + s * 256 + lane * 4);
            w1r[s] = *(const float4*)(w1p + c * CK + s * 256 + lane * 4);
        }

        __syncthreads();                          // drains vmcnt: A in LDS, W in regs

        // barrier-free, wait-free compute: pure ds_read_b128 + FMA
        #pragma unroll
        for (int s = 0; s < 8; ++s) {
            #pragma unroll
            for (int br = 0; br < 16; ++br) {
                const float4 a4 = *(const float4*)&als[br * LR + s * 256 + lane * 4];
                acc0[br] += w0r[s].x*a4.x + w0r[s].y*a4.y + w0r[s].z*a4.z + w0r[s].w*a4.w;
                acc1[br] += w1r[s].x*a4.x + w1r[s].y*a4.y + w1r[s].z*a4.z + w1r[s].w*a4.w;
            }
        }
    }

    // full-wave butterfly: every lane ends with complete sums
    #pragma unroll
    for (int off = 32; off > 0; off >>= 1) {
        #pragma unroll
        for (int i = 0; i < 16; ++i) {
            acc0[i] += __shfl_xor(acc0[i], off, 64);
            acc1[i] += __shfl_xor(acc1[i], off, 64);
        }
    }

    const bool isw0 = (lane == 0), isw1 = (lane == 32);
    if (isw0 || isw1) {
        const int o = isw0 ? col0 : col1;
        const float bs = bias[o];
        #pragma unroll
        for (int i = 0; i < 16; ++i) {
            float s = (isw0 ? acc0[i] : acc1[i]) + bs;
            if (MODE == 0) {
                s = s / (1.0f + expf(-s));        // silu
                out[(size_t)i * HALF + o] = s;    // H b-major [16][HALF]
            } else {
                s = tanhf(s);
                out[(size_t)i * (HALF * 2) + o * 2 + g] = s;
            }
        }
    }
}

extern "C" void kernel_launch(void* const* d_in, const int* in_sizes, int n_in,
                              void* d_out, int out_size, void* d_ws, size_t ws_size,
                              hipStream_t stream) {
    const float* x     = (const float*)d_in[0];
    const float* taper = (const float*)d_in[1];
    const float* cW1   = (const float*)d_in[2];
    const float* cb1   = (const float*)d_in[3];
    const float* cW2   = (const float*)d_in[4];
    const float* cb2   = (const float*)d_in[5];
    const float* pW1   = (const float*)d_in[6];
    const float* pb1   = (const float*)d_in[7];
    const float* pW2   = (const float*)d_in[8];
    const float* pb2   = (const float*)d_in[9];
    float* out = (float*)d_out;
    float* ws  = (float*)d_ws;

    float* phases_b = ws;                         // [16][4096]
    float* tdiff_b  = ws + 65536;                 // [16][4096]
    float* H1_b     = ws + 131072;                // [16][2048]
    float* H2_b     = ws + 163840;                // [16][2048]

    phase_tdiff_kernel<<<BB * TT / 4, 256, 0, stream>>>(x, taper, phases_b, tdiff_b);
    gemm_kernel<TT, 0><<<256, 512, 0, stream>>>(phases_b, cW1, cb1, H1_b,
                                                tdiff_b, pW1, pb1, H2_b);
    gemm_kernel<HALF, 1><<<256, 512, 0, stream>>>(H1_b, cW2, cb2, out,
                                                  H2_b, pW2, pb2, out);
}

// Round 18
// 113.538 us; speedup vs baseline: 1.8300x; 1.8300x over previous
//
#include <hip/hip_runtime.h>
#include <math.h>

#define BB 16
#define TT 4096
#define EE 1024
#define HALF 2048
#define WIN 15
#define EPSF 1e-6f
#define PI_F   3.14159265358979323846f
#define PIO2_F 1.57079632679489662f

// Minimal-issue branchless asin of clamp(t): ~18 VALU slots, raw HW sqrt.
__device__ __forceinline__ float asin_clamped(float t, float LO, float HI) {
    float c  = __builtin_amdgcn_fmed3f(t, LO, HI);   // clamp (1 op, no NaN here)
    float a  = fabsf(c);
    float z1 = c * c;
    float z2 = fmaf(a, -0.5f, 0.5f);                 // (1-a)/2
    bool big = a > 0.5f;
    float z  = big ? z2 : z1;
    float sq;
    asm("v_sqrt_f32 %0, %1" : "=v"(sq) : "v"(z2));   // raw, no IEEE fixup chain
    float s  = big ? sq : a;                         // s in [0, 0.5]
    float p = fmaf(z, 4.2163199048e-2f, 2.4181311049e-2f);
    p = fmaf(z, p, 4.5470025998e-2f);
    p = fmaf(z, p, 7.4953002686e-2f);
    p = fmaf(z, p, 1.6666752422e-1f);
    float r  = fmaf(s * z, p, s);                    // asin(s)
    float rb = fmaf(-2.0f, r, PIO2_F);               // pi/2 - 2*asin(s)
    r = big ? rb : r;
    return copysignf(r, c);
}

// ---------------------------------------------------------------------------
// Phase + fused tdiff (R15 frontier, verbatim): wave per row, b-major out.
// ---------------------------------------------------------------------------
__global__ void phase_tdiff_kernel(const float* __restrict__ x,
                                   const float* __restrict__ taper,
                                   float* __restrict__ phases_b,
                                   float* __restrict__ tdiff_b) {
    const int wave = threadIdx.x >> 6;
    const int lane = threadIdx.x & 63;
    const int row  = blockIdx.x * 4 + wave;      // [0, B*T)
    const int b = row >> 12;
    const int t = row & (TT - 1);
    const float tap = taper[t];
    const float* xr = x + (size_t)row * EE;

    float xd = 0.0f, tapd = 0.0f;
    const int td = t - lane;
    const bool do_d = (lane >= 1) && (lane <= WIN) && (lane <= t);
    if (do_d) {
        xd   = x[((size_t)b * TT + td) * EE];    // element 0 of row t-lane
        tapd = taper[td];
    }

    const float c0 = xr[0] * tap;
    const float r = fabsf(c0) + EPSF;
    const float scale = tap / r;
    const float start = (c0 >= 0.0f) ? 0.0f : PI_F;
    const float LO = -1.0f + EPSF, HI = 1.0f - EPSF;

    const float4* xr4 = (const float4*)xr;
    float sum = 0.0f;
    #pragma unroll
    for (int j = 0; j < 4; ++j) {
        float4 v = xr4[j * 64 + lane];
        float a0 = asin_clamped(v.x * scale, LO, HI);
        if ((j | lane) == 0) a0 = 0.0f;          // element 0 excluded
        sum += a0;
        sum += asin_clamped(v.y * scale, LO, HI);
        sum += asin_clamped(v.z * scale, LO, HI);
        sum += asin_clamped(v.w * scale, LO, HI);
    }
    #pragma unroll
    for (int off = 32; off > 0; off >>= 1)
        sum += __shfl_xor(sum, off, 64);

    float contrib = do_d ? ((float)lane * xd * tapd) : 0.0f;
    #pragma unroll
    for (int off = 8; off > 0; off >>= 1)
        contrib += __shfl_xor(contrib, off, 64);

    if (lane == 0) {
        phases_b[b * TT + t] = start + sum;
        const int s = (t < WIN) ? t : WIN;
        const float norm = 0.5f * (float)s * (float)(s + 1);
        tdiff_b[b * TT + t] = (norm > 0.0f) ? (contrib / norm) : 0.0f;
    }
}

// ---------------------------------------------------------------------------
// GEMM (M=16), REGISTER-ONLY: no LDS, no barriers, no ds_read. 512 blocks x
// 128 threads; 2 independent waves per block; 4 output cols per wave. Each
// lane holds a 4-k slice of all 16 A-rows in registers (16 float4), plus 4
// weight float4s, double-buffered across a 2-deep software pipeline (named
// even/odd register sets -> static indices; compiler emits exact counted
// waitcnts). A wave only ever waits on its OWN loads issued one full tile
// earlier — the lockstep stall of the barrier'd variants is gone.
// MODE 0: silu -> H_b[b*HALF + o].  MODE 1: tanh -> out[b*4096 + o*2 + g].
// ---------------------------------------------------------------------------
template <int K, int MODE>
__global__ void __launch_bounds__(128, 1)
gemm_kernel(const float* __restrict__ A0, const float* __restrict__ W0,
            const float* __restrict__ bias0, float* __restrict__ out0,
            const float* __restrict__ A1, const float* __restrict__ W1,
            const float* __restrict__ bias1, float* __restrict__ out1) {
    constexpr int KT = 256;                       // k per tile: 1 float4/lane/row
    constexpr int NT = K / KT;                    // 16 (G1) / 8 (G2): even

    const int nb = HALF / 8;                      // 256 blocks per problem
    const int g = blockIdx.x / nb;
    const int obase = (blockIdx.x % nb) * 8;

    const float* A    = g ? A1 : A0;
    const float* W    = g ? W1 : W0;
    const float* bias = g ? bias1 : bias0;
    float* out        = g ? out1 : out0;

    const int wv   = threadIdx.x >> 6;            // 0..1
    const int lane = threadIdx.x & 63;
    const int cb   = obase + wv * 4;              // wave's first col
    const float* ap = A + lane * 4;               // + r*K + t*KT
    const float* wp = W + (size_t)cb * K + lane * 4;  // + c*K + t*KT

#define LOADA(AR, T) do {                                                 \
        _Pragma("unroll")                                                 \
        for (int r = 0; r < 16; ++r)                                      \
            AR[r] = *(const float4*)(ap + (size_t)r * K + (size_t)(T) * KT); \
    } while (0)

#define LOADWX(WR, T) do {                                                \
        _Pragma("unroll")                                                 \
        for (int c = 0; c < 4; ++c)                                       \
            WR[c] = *(const float4*)(wp + (size_t)c * K + (size_t)(T) * KT); \
    } while (0)

#define COMP(AR, WR) do {                                                 \
        _Pragma("unroll")                                                 \
        for (int r = 0; r < 16; ++r) {                                    \
            _Pragma("unroll")                                             \
            for (int c = 0; c < 4; ++c)                                   \
                acc[c][r] += WR[c].x*AR[r].x + WR[c].y*AR[r].y            \
                           + WR[c].z*AR[r].z + WR[c].w*AR[r].w;           \
        }                                                                 \
    } while (0)

    float acc[4][16];
    #pragma unroll
    for (int c = 0; c < 4; ++c)
        #pragma unroll
        for (int r = 0; r < 16; ++r) acc[c][r] = 0.0f;

    float4 aA[16], aB[16], wA[4], wB[4];

    LOADA(aA, 0);
    LOADWX(wA, 0);

    #pragma unroll 1
    for (int t = 0; t < NT; t += 2) {
        LOADA(aB, t + 1);                         // prefetch odd tile
        LOADWX(wB, t + 1);
        COMP(aA, wA);                             // waits only on tile-t loads
        if (t + 2 < NT) {
            LOADA(aA, t + 2);                     // prefetch next even tile
            LOADWX(wA, t + 2);
        }
        COMP(aB, wB);
    }

#undef LOADA
#undef LOADWX
#undef COMP

    // 64-lane butterfly: every lane ends with the complete K-sums
    #pragma unroll
    for (int off = 32; off > 0; off >>= 1) {
        #pragma unroll
        for (int c = 0; c < 4; ++c)
            #pragma unroll
            for (int r = 0; r < 16; ++r)
                acc[c][r] += __shfl_xor(acc[c][r], off, 64);
    }

    // lanes 0,16,32,48 write cols cb+0..3 (deterministic, no LDS)
    if ((lane & 15) == 0) {
        const int c = lane >> 4;
        const int o = cb + c;
        const float bs = bias[o];
        #pragma unroll
        for (int r = 0; r < 16; ++r) {
            float s = acc[c][r] + bs;
            if (MODE == 0) {
                s = s / (1.0f + expf(-s));        // silu
                out[(size_t)r * HALF + o] = s;    // H b-major [16][HALF]
            } else {
                s = tanhf(s);
                out[(size_t)r * (HALF * 2) + o * 2 + g] = s;
            }
        }
    }
}

extern "C" void kernel_launch(void* const* d_in, const int* in_sizes, int n_in,
                              void* d_out, int out_size, void* d_ws, size_t ws_size,
                              hipStream_t stream) {
    const float* x     = (const float*)d_in[0];
    const float* taper = (const float*)d_in[1];
    const float* cW1   = (const float*)d_in[2];
    const float* cb1   = (const float*)d_in[3];
    const float* cW2   = (const float*)d_in[4];
    const float* cb2   = (const float*)d_in[5];
    const float* pW1   = (const float*)d_in[6];
    const float* pb1   = (const float*)d_in[7];
    const float* pW2   = (const float*)d_in[8];
    const float* pb2   = (const float*)d_in[9];
    float* out = (float*)d_out;
    float* ws  = (float*)d_ws;

    float* phases_b = ws;                         // [16][4096]
    float* tdiff_b  = ws + 65536;                 // [16][4096]
    float* H1_b     = ws + 131072;                // [16][2048]
    float* H2_b     = ws + 163840;                // [16][2048]

    phase_tdiff_kernel<<<BB * TT / 4, 256, 0, stream>>>(x, taper, phases_b, tdiff_b);
    gemm_kernel<TT, 0><<<512, 128, 0, stream>>>(phases_b, cW1, cb1, H1_b,
                                                tdiff_b, pW1, pb1, H2_b);
    gemm_kernel<HALF, 1><<<512, 128, 0, stream>>>(H1_b, cW2, cb2, out,
                                                  H2_b, pW2, pb2, out);
}